// Round 7
// baseline (207.728 us; speedup 1.0000x reference)
//
#include <hip/hip_runtime.h>
#include <float.h>

// out[m,n] = max_k min(x[m,k], w[k,n])  — tropical matmul, M=1024 K=512 N=512 fp32.
//
// R7 = MEASUREMENT PROBE. R4/R5/R6 (three structurally different kernels:
// smem-x/16w-CU, 32w-CU, readlane-x/low-VMEM) all landed at dur ~78-80us and
// the kernel vanished from top-5 (ws-poison fills at 41us dominate). Theory
// is unconstrained without per-kernel counters. Since max is IDEMPOTENT,
// re-scanning K `reps` times is numerically a no-op: wrap R6's K-scan in a
// runtime rep-loop (runtime arg so the compiler can't collapse it).
//   dur ~= overhead + reps * k_kernel  ->  k = (dur - 78) / 7 with reps=8,
// and the 8x kernel re-enters top-5, exposing VALUBusy/VGPR/Occupancy.

#define MDIM 1024
#define KDIM 512
#define NDIM 512
#define MB 8      // m-rows per block tile
#define NT 256    // n-cols per block tile (4 per lane)
#define KW 64     // k per wave (8 waves cover K=512)

__device__ __forceinline__ float bcast(float v, int srcLane) {
    return __int_as_float(__builtin_amdgcn_readlane(__float_as_int(v), srcLane));
}

__global__ __launch_bounds__(512) void tropical_rl_x8(
    const float* __restrict__ x,
    const float* __restrict__ w,
    float* __restrict__ out,
    int reps)
{
    const int tid  = threadIdx.x;
    const int lane = tid & 63;
    const int wv   = tid >> 6;              // 0..7: k-slice of this wave
    const int m0   = blockIdx.x * MB;
    const int n0   = blockIdx.y * NT;
    const int k0   = wv * KW;

    __shared__ float red[MB][NT];           // 8 KB combine buffer
    {
        float4* r4 = (float4*)&red[0][0];   // 512 float4s, 512 threads
        float4 z; z.x = z.y = z.z = z.w = 0.0f;
        r4[tid] = z;
    }

    // x preload: xreg[r] = x[m0+r][k0+lane]  (8 coalesced 256B loads/wave)
    float xreg[MB];
#pragma unroll
    for (int r = 0; r < MB; ++r)
        xreg[r] = x[(size_t)(m0 + r) * KDIM + k0 + lane];

#define WROW(kk) (((const float4*)(w + (size_t)(k0 + (kk)) * NDIM + n0))[lane])

    float acc[MB][4];
#pragma unroll
    for (int r = 0; r < MB; ++r)
#pragma unroll
        for (int j = 0; j < 4; ++j) acc[r][j] = 0.0f;

    for (int rep = 0; rep < reps; ++rep) {   // idempotent: max(a,a)=a
        float4 wA = WROW(0), wB = WROW(1);
        float4 wC = WROW(2), wD = WROW(3);

#pragma unroll 2
        for (int k = 0; k < KW; k += 2) {
            const int kp = (k + 4 < KW) ? (k + 4) : (KW - 2);   // clamped prefetch
            float4 wE = WROW(kp), wF = WROW(kp + 1);

            float xb0[MB], xb1[MB];
#pragma unroll
            for (int r = 0; r < MB; ++r) {
                xb0[r] = bcast(xreg[r], k);
                xb1[r] = bcast(xreg[r], k + 1);
            }
#pragma unroll
            for (int r = 0; r < MB; ++r) {
                float a0 = acc[r][0], a1 = acc[r][1], a2 = acc[r][2], a3 = acc[r][3];
                a0 = fmaxf(fmaxf(a0, fminf(xb0[r], wA.x)), fminf(xb1[r], wB.x));
                a1 = fmaxf(fmaxf(a1, fminf(xb0[r], wA.y)), fminf(xb1[r], wB.y));
                a2 = fmaxf(fmaxf(a2, fminf(xb0[r], wA.z)), fminf(xb1[r], wB.z));
                a3 = fmaxf(fmaxf(a3, fminf(xb0[r], wA.w)), fminf(xb1[r], wB.w));
                acc[r][0] = a0; acc[r][1] = a1; acc[r][2] = a2; acc[r][3] = a3;
            }
            wA = wC; wB = wD; wC = wE; wD = wF;
        }
    }
#undef WROW

    __syncthreads();   // red[] zero-init visible to all

    // combine the 8 k-split partials: LDS atomic max on float bits
    // (valid: inputs uniform[0,1) -> all partials >= 0 -> uint order == float order)
#pragma unroll
    for (int r = 0; r < MB; ++r)
#pragma unroll
        for (int j = 0; j < 4; ++j)
            atomicMax((unsigned int*)&red[r][4 * lane + j],
                      __float_as_uint(acc[r][j]));

    __syncthreads();

    // write out: 2048 floats = 512 float4s, one per thread, coalesced
    {
        const int r  = tid >> 6;            // 0..7
        const int c4 = tid & 63;            // 0..63 -> 4 cols each
        float4 v = ((const float4*)&red[r][0])[c4];
        *(float4*)(out + (size_t)(m0 + r) * NDIM + n0 + 4 * c4) = v;
    }
}

extern "C" void kernel_launch(void* const* d_in, const int* in_sizes, int n_in,
                              void* d_out, int out_size, void* d_ws, size_t ws_size,
                              hipStream_t stream) {
    const float* x = (const float*)d_in[0];   // (1024, 512)
    const float* w = (const float*)d_in[1];   // (512, 512)
    float* out = (float*)d_out;               // (1024, 512)

    dim3 grid(MDIM / MB, NDIM / NT);          // 128 x 2 = 256 blocks
    tropical_rl_x8<<<grid, dim3(512), 0, stream>>>(x, w, out, 8);
}

// Round 8
// 189.363 us; speedup vs baseline: 1.0970x; 1.0970x over previous
//
#include <hip/hip_runtime.h>
#include <float.h>

// out[m,n] = max_k min(x[m,k], w[k,n])  — tropical matmul, M=1024 K=512 N=512 fp32.
//
// R8, from R7's probe (VALUBusy 81%, VGPR=64, 393K LDS conflicts, fixed~21us):
//  (a) __launch_bounds__(512,2): R7's implicit 64-VGPR cap starved the loop
//      (~90 regs live) -> compiler serialization, ~2.4x VALU bloat. Grid is
//      1 block/CU regardless, so allow 256 VGPRs. K-loop fully unrolled,
//      readlane with compile-time lane index, no clamped-prefetch cndmask.
//  (b) atomicMax epilogue (serialized, the ~21us fixed cost) -> barrier-once
//      LDS tree reduce (64 KB): 8 ds_write_b128 + 8 ds_read_b128 + 28 max.
// Core kept from R6: 8-row register reuse of each w float4 (delivery-BW
// floor: w bytes/output-k = 0.5B -> 134 MB total), x broadcast via readlane.

#define MDIM 1024
#define KDIM 512
#define NDIM 512
#define MB 8      // m-rows per block tile (register reuse factor for w)
#define NT 256    // n-cols per block tile (4 per lane)
#define KW 64     // k per wave (8 waves cover K=512)
#define NWAVE 8

__device__ __forceinline__ float bcastc(float v, int srcLane) {
    return __int_as_float(__builtin_amdgcn_readlane(__float_as_int(v), srcLane));
}

__global__ __launch_bounds__(512, 2) void tropical_r8(
    const float* __restrict__ x,
    const float* __restrict__ w,
    float* __restrict__ out)
{
    const int tid  = threadIdx.x;
    const int lane = tid & 63;
    const int wv   = tid >> 6;              // 0..7: k-slice of this wave
    const int m0   = blockIdx.x * MB;
    const int n0   = blockIdx.y * NT;
    const int k0   = wv * KW;

    __shared__ float red[NWAVE][MB][NT];    // 64 KB tree-reduce buffer

    // x preload: xreg[r] = x[m0+r][k0+lane]  (8 coalesced 256B loads/wave)
    float xreg[MB];
#pragma unroll
    for (int r = 0; r < MB; ++r)
        xreg[r] = x[(size_t)(m0 + r) * KDIM + k0 + lane];

    // w row k (this lane's 4 n's) lives at wb[k * 128]
    const float4* __restrict__ wb =
        (const float4*)(w + (size_t)k0 * NDIM + n0) + lane;

    float acc[MB][4];
#pragma unroll
    for (int r = 0; r < MB; ++r)
#pragma unroll
        for (int j = 0; j < 4; ++j) acc[r][j] = 0.0f;   // inputs in [0,1)

    float4 cur0 = wb[0 * 128], cur1 = wb[1 * 128];
    float4 cur2 = wb[2 * 128], cur3 = wb[3 * 128];

#pragma unroll
    for (int kc = 0; kc < KW; kc += 4) {
        float4 nx0, nx1, nx2, nx3;
        if (kc + 4 < KW) {                  // compile-time after full unroll
            nx0 = wb[(kc + 4) * 128]; nx1 = wb[(kc + 5) * 128];
            nx2 = wb[(kc + 6) * 128]; nx3 = wb[(kc + 7) * 128];
        }
#pragma unroll
        for (int p = 0; p < 2; ++p) {       // k-pairs (kc,kc+1), (kc+2,kc+3)
            const float4 wlo = p ? cur2 : cur0;
            const float4 whi = p ? cur3 : cur1;
            const int kk = kc + 2 * p;      // compile-time readlane index
            float xb0[MB], xb1[MB];
#pragma unroll
            for (int r = 0; r < MB; ++r) {
                xb0[r] = bcastc(xreg[r], kk);
                xb1[r] = bcastc(xreg[r], kk + 1);
            }
#pragma unroll
            for (int r = 0; r < MB; ++r) {  // 2 v_min + 1 v_max3 per acc
                acc[r][0] = fmaxf(acc[r][0],
                                  fmaxf(fminf(xb0[r], wlo.x), fminf(xb1[r], whi.x)));
                acc[r][1] = fmaxf(acc[r][1],
                                  fmaxf(fminf(xb0[r], wlo.y), fminf(xb1[r], whi.y)));
                acc[r][2] = fmaxf(acc[r][2],
                                  fmaxf(fminf(xb0[r], wlo.z), fminf(xb1[r], whi.z)));
                acc[r][3] = fmaxf(acc[r][3],
                                  fmaxf(fminf(xb0[r], wlo.w), fminf(xb1[r], whi.w)));
            }
        }
        if (kc + 4 < KW) { cur0 = nx0; cur1 = nx1; cur2 = nx2; cur3 = nx3; }
    }

    // tree combine of the 8 k-split partials (no atomics)
#pragma unroll
    for (int r = 0; r < MB; ++r) {
        float4 v; v.x = acc[r][0]; v.y = acc[r][1]; v.z = acc[r][2]; v.w = acc[r][3];
        ((float4*)&red[wv][r][0])[lane] = v;
    }
    __syncthreads();

    {
        const int r  = tid >> 6;            // 0..7
        const int c4 = tid & 63;            // 0..63 -> one float4 each
        float4 v = ((const float4*)&red[0][r][0])[c4];
#pragma unroll
        for (int q = 1; q < NWAVE; ++q) {
            float4 u = ((const float4*)&red[q][r][0])[c4];
            v.x = fmaxf(v.x, u.x); v.y = fmaxf(v.y, u.y);
            v.z = fmaxf(v.z, u.z); v.w = fmaxf(v.w, u.w);
        }
        *(float4*)(out + (size_t)(m0 + r) * NDIM + n0 + 4 * c4) = v;
    }
}

extern "C" void kernel_launch(void* const* d_in, const int* in_sizes, int n_in,
                              void* d_out, int out_size, void* d_ws, size_t ws_size,
                              hipStream_t stream) {
    const float* x = (const float*)d_in[0];   // (1024, 512)
    const float* w = (const float*)d_in[1];   // (512, 512)
    float* out = (float*)d_out;               // (1024, 512)

    dim3 grid(MDIM / MB, NDIM / NT);          // 128 x 2 = 256 blocks
    tropical_r8<<<grid, dim3(512), 0, stream>>>(x, w, out);
}

// Round 9
// 77.078 us; speedup vs baseline: 2.6950x; 2.4568x over previous
//
#include <hip/hip_runtime.h>

// out[m,n] = max_k min(x[m,k], w[k,n])  — tropical matmul, M=1024 K=512 N=512 fp32.
//
// R9 = R7's ROLLED dbuf loop + 256-VGPR budget + R8's tree epilogue.
//  - R7 probe: loop VALU-issue-bound (VALUBusy 81%) at VGPR=64 -> ~3x instr
//    bloat (live set ~82 regs). Fix: __launch_bounds__(512,2) (cap 256).
//  - R8 lesson: FULL unroll of the k-loop let the compiler hoist all 64
//    w-loads -> 200+ MB scratch spill. Keep the loop rolled, #pragma unroll 2.
//  - Epilogue: barrier-once LDS tree reduce (R7's LDS atomicMax was ~21us of
//    serialized conflicts).
// Core: 8-row register reuse of each w float4; x broadcast via v_readlane
// (k uniform -> SGPR index, result in SGPR, used as the 1 SGPR operand of
// v_min_f32). Inner op: min,min,v_max3 = 1.5 VALU/position.
// Issue floor: 2048 waves x ~3700 instr x 2cy / 1024 SIMDs ~= 6.2 us.

#define MDIM 1024
#define KDIM 512
#define NDIM 512
#define MB 8      // m-rows per block tile (register reuse factor for w)
#define NT 256    // n-cols per block tile (4 per lane)
#define KW 64     // k per wave (8 waves cover K=512)
#define NWAVE 8

__device__ __forceinline__ float bcast(float v, int srcLane) {
    return __int_as_float(__builtin_amdgcn_readlane(__float_as_int(v), srcLane));
}

__global__ __launch_bounds__(512, 2) void tropical_r9(
    const float* __restrict__ x,
    const float* __restrict__ w,
    float* __restrict__ out)
{
    const int tid  = threadIdx.x;
    const int lane = tid & 63;
    const int wv   = tid >> 6;              // 0..7: k-slice of this wave
    const int m0   = blockIdx.x * MB;
    const int n0   = blockIdx.y * NT;
    const int k0   = wv * KW;

    __shared__ float red[NWAVE][MB][NT];    // 64 KB tree-reduce buffer

    // x preload: xreg[r] = x[m0+r][k0+lane]  (8 coalesced 256B loads/wave)
    float xreg[MB];
#pragma unroll
    for (int r = 0; r < MB; ++r)
        xreg[r] = x[(size_t)(m0 + r) * KDIM + k0 + lane];

    // w row k (this lane's 4 n's) lives at wb[k * 128]
    const float4* __restrict__ wb =
        (const float4*)(w + (size_t)k0 * NDIM + n0) + lane;

    float acc[MB][4];
#pragma unroll
    for (int r = 0; r < MB; ++r)
#pragma unroll
        for (int j = 0; j < 4; ++j) acc[r][j] = 0.0f;   // inputs in [0,1)

    float4 cA = wb[0 * 128], cB = wb[1 * 128];
    float4 cC = wb[2 * 128], cD = wb[3 * 128];

#pragma unroll 2
    for (int kc = 0; kc < KW; kc += 4) {    // rolled: 16 iterations
        float4 nA, nB, nC, nD;
        if (kc + 4 < KW) {
            nA = wb[(size_t)(kc + 4) * 128]; nB = wb[(size_t)(kc + 5) * 128];
            nC = wb[(size_t)(kc + 6) * 128]; nD = wb[(size_t)(kc + 7) * 128];
        }
        float xb0[MB], xb1[MB], xb2[MB], xb3[MB];
#pragma unroll
        for (int r = 0; r < MB; ++r) {
            xb0[r] = bcast(xreg[r], kc);
            xb1[r] = bcast(xreg[r], kc + 1);
            xb2[r] = bcast(xreg[r], kc + 2);
            xb3[r] = bcast(xreg[r], kc + 3);
        }
#pragma unroll
        for (int r = 0; r < MB; ++r) {      // min,min,max3 per (col, 2k)
            acc[r][0] = fmaxf(acc[r][0], fmaxf(fminf(xb0[r], cA.x), fminf(xb1[r], cB.x)));
            acc[r][1] = fmaxf(acc[r][1], fmaxf(fminf(xb0[r], cA.y), fminf(xb1[r], cB.y)));
            acc[r][2] = fmaxf(acc[r][2], fmaxf(fminf(xb0[r], cA.z), fminf(xb1[r], cB.z)));
            acc[r][3] = fmaxf(acc[r][3], fmaxf(fminf(xb0[r], cA.w), fminf(xb1[r], cB.w)));
            acc[r][0] = fmaxf(acc[r][0], fmaxf(fminf(xb2[r], cC.x), fminf(xb3[r], cD.x)));
            acc[r][1] = fmaxf(acc[r][1], fmaxf(fminf(xb2[r], cC.y), fminf(xb3[r], cD.y)));
            acc[r][2] = fmaxf(acc[r][2], fmaxf(fminf(xb2[r], cC.z), fminf(xb3[r], cD.z)));
            acc[r][3] = fmaxf(acc[r][3], fmaxf(fminf(xb2[r], cC.w), fminf(xb3[r], cD.w)));
        }
        cA = nA; cB = nB; cC = nC; cD = nD;
    }

    // tree combine of the 8 k-split partials (no atomics)
#pragma unroll
    for (int r = 0; r < MB; ++r) {
        float4 v; v.x = acc[r][0]; v.y = acc[r][1]; v.z = acc[r][2]; v.w = acc[r][3];
        ((float4*)&red[wv][r][0])[lane] = v;
    }
    __syncthreads();

    {
        const int r  = tid >> 6;            // 0..7
        const int c4 = tid & 63;            // one float4 each
        float4 v = ((const float4*)&red[0][r][0])[c4];
#pragma unroll
        for (int q = 1; q < NWAVE; ++q) {
            float4 u = ((const float4*)&red[q][r][0])[c4];
            v.x = fmaxf(v.x, u.x); v.y = fmaxf(v.y, u.y);
            v.z = fmaxf(v.z, u.z); v.w = fmaxf(v.w, u.w);
        }
        *(float4*)(out + (size_t)(m0 + r) * NDIM + n0 + 4 * c4) = v;
    }
}

extern "C" void kernel_launch(void* const* d_in, const int* in_sizes, int n_in,
                              void* d_out, int out_size, void* d_ws, size_t ws_size,
                              hipStream_t stream) {
    const float* x = (const float*)d_in[0];   // (1024, 512)
    const float* w = (const float*)d_in[1];   // (512, 512)
    float* out = (float*)d_out;               // (1024, 512)

    dim3 grid(MDIM / MB, NDIM / NT);          // 128 x 2 = 256 blocks
    tropical_r9<<<grid, dim3(512), 0, stream>>>(x, w, out);
}